// Round 8
// baseline (411.560 us; speedup 1.0000x reference)
//
#include <hip/hip_runtime.h>

// MMD loss, N=4096 per side, D=256, fp32.
// R8: split-bf16 MFMA Gram (hh+hl+lh; ll dropped), tiled hi/lo planes (R6),
//     barrier-free K-loop (R7) + EXPLICIT register double-buffer: next k-step's
//     16 fragments are loaded before the current 48-MFMA burst (one
//     sched_barrier(0) per k-step pins loads above MFMAs) -> covers ~200-400cyc
//     L2/LLC latency that left MfmaUtil at 28% in R7 (VGPR=84 = no prefetch).
//     MFMA order pass-major: 16 independent MFMAs between acc reuses.
//     Launch count 4 -> 2: k_scale fused into k_conv, k_fin fused into k_pairs
//     (device-scope last-finisher: threadfence -> atomic ticket -> winner).
//     Counters zeroed via one hipMemsetAsync (graph-capturable).

#define NROWS 8192
#define HALF  4096
#define DIM   256
#define BM    128
#define CONVB 256         // k_conv blocks; 32 rows each (quarter panel)
#define NTILE 2080        // upper-tri 64x64 tile count for 128-tiles

typedef __bf16 bf16x8 __attribute__((ext_vector_type(8)));
typedef float f32x4 __attribute__((ext_vector_type(4)));
typedef unsigned short ushort8 __attribute__((ext_vector_type(8)));

__device__ __forceinline__ const float* row_ptr(const float* src, const float* tgt, int r) {
    return (r < HALF) ? (src + (size_t)r * DIM) : (tgt + (size_t)(r - HALF) * DIM);
}

__device__ __forceinline__ unsigned short bf16_rne(float x) {
    unsigned int u = __builtin_bit_cast(unsigned int, x);
    return (unsigned short)((u + 0x7FFFu + ((u >> 16) & 1u)) >> 16);
}

// --- Phase 0: fp32 -> hi/lo planes (tiled) + sq[] + colsum partials; the
//     last-finishing block computes the bandwidth scale (fused k_scale). ---
// Tiled plane layout: 16B-granule index of (global row R, k-granule g) =
//   (R>>7)*4096 + g*128 + (R&127)        [panel-major, granule-major inside]
__global__ __launch_bounds__(256) void k_conv(const float* __restrict__ src,
                                              const float* __restrict__ tgt,
                                              unsigned short* __restrict__ hi,
                                              unsigned short* __restrict__ lo,
                                              float* __restrict__ sq,
                                              float* __restrict__ part,
                                              int* __restrict__ cnt,
                                              float* __restrict__ scale) {
    __shared__ __align__(16) unsigned short sh_hi[32 * 32 * 8];  // 16 KB
    __shared__ __align__(16) unsigned short sh_lo[32 * 32 * 8];  // 16 KB
    __shared__ float4 cs[4][64];
    __shared__ double sh[256];
    __shared__ int isLast;

    int w = threadIdx.x >> 6, lane = threadIdx.x & 63;
    int r0 = blockIdx.x * 32;                       // 32 rows per block
    int g  = lane >> 1, j = lane & 1;               // lane's float4 = half-granule
    float4 csum = {0.f, 0.f, 0.f, 0.f};
    #pragma unroll
    for (int i = 0; i < 8; ++i) {
        int rl  = w * 8 + i;                        // local row 0..31
        int row = r0 + rl;
        const float* rp = row_ptr(src, tgt, row);
        float4 v = ((const float4*)rp)[lane];       // coalesced: 64 lanes * 16 B
        float xs[4] = {v.x, v.y, v.z, v.w};
        unsigned short hs[4], ls[4];
        #pragma unroll
        for (int k = 0; k < 4; ++k) {
            unsigned short hh = bf16_rne(xs[k]);
            float hr = __builtin_bit_cast(float, (unsigned int)hh << 16);
            hs[k] = hh;
            ls[k] = bf16_rne(xs[k] - hr);
        }
        ushort4 h4 = {hs[0], hs[1], hs[2], hs[3]};
        ushort4 l4 = {ls[0], ls[1], ls[2], ls[3]};
        int so = (g * 32 + rl) * 8 + j * 4;
        *(ushort4*)&sh_hi[so] = h4;
        *(ushort4*)&sh_lo[so] = l4;
        csum.x += v.x; csum.y += v.y; csum.z += v.z; csum.w += v.w;
        float s = v.x * v.x + v.y * v.y + v.z * v.z + v.w * v.w;
        #pragma unroll
        for (int off = 32; off; off >>= 1) s += __shfl_xor(s, off, 64);
        if (lane == 0) sq[row] = s;
    }
    __syncthreads();
    // Coalesced tiled write-out: 1024 chunks of 16 B per plane.
    int panel = blockIdx.x >> 2, quarter = blockIdx.x & 3;
    #pragma unroll
    for (int c = threadIdx.x; c < 1024; c += 256) {
        int gg = c >> 5, r = c & 31;
        size_t goff = (((size_t)panel * 32 + gg) * 128 + quarter * 32 + r) * 8;
        *(ushort8*)&hi[goff] = *(const ushort8*)&sh_hi[c * 8];
        *(ushort8*)&lo[goff] = *(const ushort8*)&sh_lo[c * 8];
    }
    // colsum partials
    cs[w][lane] = csum;
    __syncthreads();
    if (w == 0) {
        float4 a = cs[0][lane], b = cs[1][lane], c = cs[2][lane], d = cs[3][lane];
        float4 tot = {a.x + b.x + c.x + d.x, a.y + b.y + c.y + d.y,
                      a.z + b.z + c.z + d.z, a.w + b.w + c.w + d.w};
        *(float4*)&part[(size_t)blockIdx.x * DIM + lane * 4] = tot;
    }

    // ---- last-finisher computes the bandwidth scale (fused k_scale)
    __threadfence();
    if (threadIdx.x == 0) isLast = (atomicAdd(cnt, 1) == CONVB - 1);
    __syncthreads();
    if (!isLast) return;
    __threadfence();                                // acquire: see all sq/part
    int t = threadIdx.x;
    double s1 = 0.0;
    for (int i = t; i < NROWS; i += 256) s1 += (double)sq[i];
    sh[t] = s1;
    __syncthreads();
    for (int off = 128; off; off >>= 1) {
        if (t < off) sh[t] += sh[t + off];
        __syncthreads();
    }
    double S1 = sh[0];
    __syncthreads();
    float c = 0.0f;
    for (int b = 0; b < CONVB; ++b) c += part[b * DIM + t];  // coalesced
    sh[t] = (double)c * (double)c;
    __syncthreads();
    for (int off = 128; off; off >>= 1) {
        if (t < off) sh[t] += sh[t + off];
        __syncthreads();
    }
    if (t == 0) {
        double S2    = sh[0];
        double n     = (double)NROWS;
        double sumL2 = 2.0 * n * S1 - 2.0 * S2;
        double bw    = sumL2 / (n * n - n) / 4.0;   // / KERNEL_MUL^(KERNEL_NUM//2)
        // u = exp(-L2/(16*bw)) = exp2(scale * L2)
        *scale = (float)(-1.0 / (16.0 * bw * 0.69314718055994530942));
    }
}

// --- Phase 2: barrier-free split-bf16 MFMA pair kernel, reg double-buffer ---
__global__ __launch_bounds__(256, 2) void k_pairs(const unsigned short* __restrict__ hi,
                                                  const unsigned short* __restrict__ lo,
                                                  const float* __restrict__ sq,
                                                  const float* __restrict__ scale_p,
                                                  double* __restrict__ accum,
                                                  int* __restrict__ cnt,
                                                  float* __restrict__ out) {
    // Band decode: band k = bj/8; within band, bi-major, 8 consecutive columns.
    int id = blockIdx.x;
    int k = 0;
    while (k < 7 && 32 * (k + 1) * (k + 1) + 4 * (k + 1) <= id) ++k;
    int rem = id - (32 * k * k + 4 * k);
    int bi, col;
    if (rem < 64 * k) {
        bi = rem >> 3; col = rem & 7;
    } else {
        int r2 = rem - 64 * k;
        int jj = 0, c = 0;
        while (c + (8 - jj) <= r2) { c += (8 - jj); ++jj; }
        bi = 8 * k + jj; col = jj + (r2 - c);
    }
    int bj = 8 * k + col;

    __shared__ float wsum[4];
    __shared__ int isLast;

    int t    = threadIdx.x;
    int lane = t & 63;
    int w    = t >> 6;
    int wr   = w >> 1, wc = w & 1;                  // 2x2 wave grid, 64x64 each
    int lr   = lane & 15, lq = lane >> 4;
    int ro = bi * BM, co = bj * BM;

    size_t aBase = (size_t)bi * 4096 + lq * 128 + wr * 64 + lr;
    size_t bBase = (size_t)bj * 4096 + lq * 128 + wc * 64 + lr;
    const ushort8* pAh = (const ushort8*)hi + aBase;
    const ushort8* pAl = (const ushort8*)lo + aBase;
    const ushort8* pBh = (const ushort8*)hi + bBase;
    const ushort8* pBl = (const ushort8*)lo + bBase;

    f32x4 acc[4][4];
    #pragma unroll
    for (int m = 0; m < 4; ++m)
        #pragma unroll
        for (int n = 0; n < 4; ++n) acc[m][n] = (f32x4){0.f, 0.f, 0.f, 0.f};

    // Current-iteration fragments (preload k-step 0)
    bf16x8 cAH[4], cAL[4], cBH[4], cBL[4];
    #pragma unroll
    for (int m = 0; m < 4; ++m) {
        cAH[m] = __builtin_bit_cast(bf16x8, pAh[m * 16]);
        cAL[m] = __builtin_bit_cast(bf16x8, pAl[m * 16]);
        cBH[m] = __builtin_bit_cast(bf16x8, pBh[m * 16]);
        cBL[m] = __builtin_bit_cast(bf16x8, pBl[m * 16]);
    }

    #pragma unroll
    for (int it = 0; it < DIM / 32; ++it) {
        // Prefetch next k-step's fragments BEFORE the MFMA burst.
        bf16x8 nAH[4], nAL[4], nBH[4], nBL[4];
        if (it + 1 < DIM / 32) {
            int o = (it + 1) * 512;
            #pragma unroll
            for (int m = 0; m < 4; ++m) {
                nAH[m] = __builtin_bit_cast(bf16x8, pAh[o + m * 16]);
                nAL[m] = __builtin_bit_cast(bf16x8, pAl[o + m * 16]);
                nBH[m] = __builtin_bit_cast(bf16x8, pBh[o + m * 16]);
                nBL[m] = __builtin_bit_cast(bf16x8, pBl[o + m * 16]);
            }
        }
        __builtin_amdgcn_sched_barrier(0);          // pin loads above the MFMA burst
        // Pass-major MFMA: 16 independent MFMAs between reuses of any acc.
        #pragma unroll
        for (int m = 0; m < 4; ++m)
            #pragma unroll
            for (int n = 0; n < 4; ++n)
                acc[m][n] = __builtin_amdgcn_mfma_f32_16x16x32_bf16(cAH[m], cBH[n], acc[m][n], 0, 0, 0);
        #pragma unroll
        for (int m = 0; m < 4; ++m)
            #pragma unroll
            for (int n = 0; n < 4; ++n)
                acc[m][n] = __builtin_amdgcn_mfma_f32_16x16x32_bf16(cAH[m], cBL[n], acc[m][n], 0, 0, 0);
        #pragma unroll
        for (int m = 0; m < 4; ++m)
            #pragma unroll
            for (int n = 0; n < 4; ++n)
                acc[m][n] = __builtin_amdgcn_mfma_f32_16x16x32_bf16(cAL[m], cBH[n], acc[m][n], 0, 0, 0);
        // lo*lo pass dropped: ~2^-17 relative on Gram term
        if (it + 1 < DIM / 32) {
            #pragma unroll
            for (int m = 0; m < 4; ++m) {
                cAH[m] = nAH[m]; cAL[m] = nAL[m];
                cBH[m] = nBH[m]; cBL[m] = nBL[m];
            }
        }
    }

    // ---- epilogue: L2 -> sum of 5 Gaussian kernels -> reduce
    float scale = *scale_p;
    int ro_eff = ro + wr * 64, co_eff = co + wc * 64;
    float4 sqa4[4];
    float  sqbv[4];
    #pragma unroll
    for (int m = 0; m < 4; ++m) sqa4[m] = *(const float4*)&sq[ro_eff + m * 16 + lq * 4];
    #pragma unroll
    for (int n = 0; n < 4; ++n) sqbv[n] = sq[co_eff + n * 16 + lr];

    float tsum = 0.0f;
    #pragma unroll
    for (int m = 0; m < 4; ++m) {
        float sa[4] = {sqa4[m].x, sqa4[m].y, sqa4[m].z, sqa4[m].w};
        #pragma unroll
        for (int n = 0; n < 4; ++n) {
            #pragma unroll
            for (int r = 0; r < 4; ++r) {
                float L2  = sa[r] + sqbv[n] - 2.0f * acc[m][n][r];
                float u   = __builtin_amdgcn_exp2f(scale * L2);
                float u2  = u * u;
                float u4  = u2 * u2;
                float u8  = u4 * u4;
                float u16 = u8 * u8;
                tsum += u + u2 + u4 + u8 + u16;     // 5 kernel scales
            }
        }
    }

    #pragma unroll
    for (int off = 32; off; off >>= 1) tsum += __shfl_xor(tsum, off, 64);
    if (lane == 0) wsum[w] = tsum;
    __syncthreads();
    if (t == 0) {
        float tot = wsum[0] + wsum[1] + wsum[2] + wsum[3];
        float sgn = ((ro < HALF) == (co < HALF)) ? 1.0f : -1.0f;
        float wgt = (bi == bj) ? 1.0f : 2.0f;       // off-diag tiles stand for (i,j)+(j,i)
        atomicAdd(accum, (double)(sgn * wgt * tot));
    }

    // ---- last-finisher normalizes and writes the scalar output (fused k_fin)
    __threadfence();
    if (t == 0) isLast = (atomicAdd(cnt, 1) == NTILE - 1);
    __syncthreads();
    if (isLast && t == 0) {
        double v = atomicAdd(accum, 0.0);           // coherent read-back
        out[0] = (float)(v / ((double)HALF * (double)HALF));
    }
}

extern "C" void kernel_launch(void* const* d_in, const int* in_sizes, int n_in,
                              void* d_out, int out_size, void* d_ws, size_t ws_size,
                              hipStream_t stream) {
    const float* src = (const float*)d_in[0];
    const float* tgt = (const float*)d_in[1];
    float* out = (float*)d_out;

    char* ws = (char*)d_ws;
    int*    cnt1  = (int*)ws;                                    // 4 B
    int*    cnt2  = (int*)(ws + 4);                              // 4 B
    double* accum = (double*)(ws + 8);                           // 8 B
    float*  scale = (float*)(ws + 16);                           // 4 B
    float*  sq    = (float*)(ws + 64);                           // 32768 B
    float*  part  = (float*)(ws + 64 + 32768);                   // 256*256*4 B
    unsigned short* hi = (unsigned short*)(ws + 294976);         // 4 MB, 16B-aligned
    unsigned short* lo = (unsigned short*)(ws + 294976 + (size_t)NROWS * DIM * 2);

    hipMemsetAsync(ws, 0, 64, stream);              // counters + accum (+scale)
    k_conv <<<CONVB, 256, 0, stream>>>(src, tgt, hi, lo, sq, part, cnt1, scale);
    k_pairs<<<NTILE, 256, 0, stream>>>(hi, lo, sq, scale, accum, cnt2, out);
}

// Round 9
// 320.842 us; speedup vs baseline: 1.2828x; 1.2828x over previous
//
#include <hip/hip_runtime.h>

// MMD loss, N=4096 per side, D=256, fp32.
// R9: split-bf16 MFMA Gram (hh+hl+lh; ll dropped), tiled hi/lo planes (R6),
//     barrier-free K-loop (R7) + COPY-FREE static register double-buffer:
//     frag arrays indexed [it&1] with full unroll -> next k-step's 16 loads
//     issue into distinct regs before the current 48-MFMA burst; compiler
//     emits partial vmcnt(N) waits. NO sched_barrier (R8 trap, m141), NO
//     rotation copies (R8's 128-live-reg crush at VGPR=112).
//     Fused: k_scale into k_conv, k_fin into k_pairs (last-finisher tickets).

#define NROWS 8192
#define HALF  4096
#define DIM   256
#define BM    128
#define CONVB 256         // k_conv blocks; 32 rows each (quarter panel)
#define NTILE 2080        // upper-tri tile count for 128-tiles (64 bands of 8)

typedef __bf16 bf16x8 __attribute__((ext_vector_type(8)));
typedef float f32x4 __attribute__((ext_vector_type(4)));
typedef unsigned short ushort8 __attribute__((ext_vector_type(8)));

__device__ __forceinline__ const float* row_ptr(const float* src, const float* tgt, int r) {
    return (r < HALF) ? (src + (size_t)r * DIM) : (tgt + (size_t)(r - HALF) * DIM);
}

__device__ __forceinline__ unsigned short bf16_rne(float x) {
    unsigned int u = __builtin_bit_cast(unsigned int, x);
    return (unsigned short)((u + 0x7FFFu + ((u >> 16) & 1u)) >> 16);
}

// --- Phase 0: fp32 -> hi/lo planes (tiled) + sq[] + colsum partials; the
//     last-finishing block computes the bandwidth scale (fused k_scale). ---
// Tiled plane layout: 16B-granule index of (global row R, k-granule g) =
//   (R>>7)*4096 + g*128 + (R&127)        [panel-major, granule-major inside]
__global__ __launch_bounds__(256) void k_conv(const float* __restrict__ src,
                                              const float* __restrict__ tgt,
                                              unsigned short* __restrict__ hi,
                                              unsigned short* __restrict__ lo,
                                              float* __restrict__ sq,
                                              float* __restrict__ part,
                                              int* __restrict__ cnt,
                                              float* __restrict__ scale) {
    __shared__ __align__(16) unsigned short sh_hi[32 * 32 * 8];  // 16 KB
    __shared__ __align__(16) unsigned short sh_lo[32 * 32 * 8];  // 16 KB
    __shared__ float4 cs[4][64];
    __shared__ double sh[256];
    __shared__ int isLast;

    int w = threadIdx.x >> 6, lane = threadIdx.x & 63;
    int r0 = blockIdx.x * 32;                       // 32 rows per block
    int g  = lane >> 1, j = lane & 1;               // lane's float4 = half-granule
    float4 csum = {0.f, 0.f, 0.f, 0.f};
    #pragma unroll
    for (int i = 0; i < 8; ++i) {
        int rl  = w * 8 + i;                        // local row 0..31
        int row = r0 + rl;
        const float* rp = row_ptr(src, tgt, row);
        float4 v = ((const float4*)rp)[lane];       // coalesced: 64 lanes * 16 B
        float xs[4] = {v.x, v.y, v.z, v.w};
        unsigned short hs[4], ls[4];
        #pragma unroll
        for (int k = 0; k < 4; ++k) {
            unsigned short hh = bf16_rne(xs[k]);
            float hr = __builtin_bit_cast(float, (unsigned int)hh << 16);
            hs[k] = hh;
            ls[k] = bf16_rne(xs[k] - hr);
        }
        ushort4 h4 = {hs[0], hs[1], hs[2], hs[3]};
        ushort4 l4 = {ls[0], ls[1], ls[2], ls[3]};
        int so = (g * 32 + rl) * 8 + j * 4;
        *(ushort4*)&sh_hi[so] = h4;
        *(ushort4*)&sh_lo[so] = l4;
        csum.x += v.x; csum.y += v.y; csum.z += v.z; csum.w += v.w;
        float s = v.x * v.x + v.y * v.y + v.z * v.z + v.w * v.w;
        #pragma unroll
        for (int off = 32; off; off >>= 1) s += __shfl_xor(s, off, 64);
        if (lane == 0) sq[row] = s;
    }
    __syncthreads();
    // Coalesced tiled write-out: 1024 chunks of 16 B per plane.
    int panel = blockIdx.x >> 2, quarter = blockIdx.x & 3;
    #pragma unroll
    for (int c = threadIdx.x; c < 1024; c += 256) {
        int gg = c >> 5, r = c & 31;
        size_t goff = (((size_t)panel * 32 + gg) * 128 + quarter * 32 + r) * 8;
        *(ushort8*)&hi[goff] = *(const ushort8*)&sh_hi[c * 8];
        *(ushort8*)&lo[goff] = *(const ushort8*)&sh_lo[c * 8];
    }
    // colsum partials
    cs[w][lane] = csum;
    __syncthreads();
    if (w == 0) {
        float4 a = cs[0][lane], b = cs[1][lane], c = cs[2][lane], d = cs[3][lane];
        float4 tot = {a.x + b.x + c.x + d.x, a.y + b.y + c.y + d.y,
                      a.z + b.z + c.z + d.z, a.w + b.w + c.w + d.w};
        *(float4*)&part[(size_t)blockIdx.x * DIM + lane * 4] = tot;
    }

    // ---- last-finisher computes the bandwidth scale (fused k_scale)
    __threadfence();
    if (threadIdx.x == 0) isLast = (atomicAdd(cnt, 1) == CONVB - 1);
    __syncthreads();
    if (!isLast) return;
    __threadfence();                                // acquire: see all sq/part
    int t = threadIdx.x;
    double s1 = 0.0;
    for (int i = t; i < NROWS; i += 256) s1 += (double)sq[i];
    sh[t] = s1;
    __syncthreads();
    for (int off = 128; off; off >>= 1) {
        if (t < off) sh[t] += sh[t + off];
        __syncthreads();
    }
    double S1 = sh[0];
    __syncthreads();
    float c = 0.0f;
    for (int b = 0; b < CONVB; ++b) c += part[b * DIM + t];  // coalesced
    sh[t] = (double)c * (double)c;
    __syncthreads();
    for (int off = 128; off; off >>= 1) {
        if (t < off) sh[t] += sh[t + off];
        __syncthreads();
    }
    if (t == 0) {
        double S2    = sh[0];
        double n     = (double)NROWS;
        double sumL2 = 2.0 * n * S1 - 2.0 * S2;
        double bw    = sumL2 / (n * n - n) / 4.0;   // / KERNEL_MUL^(KERNEL_NUM//2)
        // u = exp(-L2/(16*bw)) = exp2(scale * L2)
        *scale = (float)(-1.0 / (16.0 * bw * 0.69314718055994530942));
    }
}

// --- Phase 2: barrier-free split-bf16 MFMA pair kernel, static dbuf regs ---
__global__ __launch_bounds__(256, 2) void k_pairs(const unsigned short* __restrict__ hi,
                                                  const unsigned short* __restrict__ lo,
                                                  const float* __restrict__ sq,
                                                  const float* __restrict__ scale_p,
                                                  double* __restrict__ accum,
                                                  int* __restrict__ cnt,
                                                  float* __restrict__ out) {
    // Band decode: band k = bj/8; within band, bi-major, 8 consecutive columns.
    int id = blockIdx.x;
    int k = 0;
    while (k < 7 && 32 * (k + 1) * (k + 1) + 4 * (k + 1) <= id) ++k;
    int rem = id - (32 * k * k + 4 * k);
    int bi, col;
    if (rem < 64 * k) {
        bi = rem >> 3; col = rem & 7;
    } else {
        int r2 = rem - 64 * k;
        int jj = 0, c = 0;
        while (c + (8 - jj) <= r2) { c += (8 - jj); ++jj; }
        bi = 8 * k + jj; col = jj + (r2 - c);
    }
    int bj = 8 * k + col;

    __shared__ float wsum[4];
    __shared__ int isLast;

    int t    = threadIdx.x;
    int lane = t & 63;
    int w    = t >> 6;
    int wr   = w >> 1, wc = w & 1;                  // 2x2 wave grid, 64x64 each
    int lr   = lane & 15, lq = lane >> 4;
    int ro = bi * BM, co = bj * BM;

    size_t aBase = (size_t)bi * 4096 + lq * 128 + wr * 64 + lr;
    size_t bBase = (size_t)bj * 4096 + lq * 128 + wc * 64 + lr;
    const ushort8* pAh = (const ushort8*)hi + aBase;
    const ushort8* pAl = (const ushort8*)lo + aBase;
    const ushort8* pBh = (const ushort8*)hi + bBase;
    const ushort8* pBl = (const ushort8*)lo + bBase;

    f32x4 acc[4][4];
    #pragma unroll
    for (int m = 0; m < 4; ++m)
        #pragma unroll
        for (int n = 0; n < 4; ++n) acc[m][n] = (f32x4){0.f, 0.f, 0.f, 0.f};

    // Static double-buffered fragments: [buf][frag], all indices constant
    // after full unroll -> pure registers, zero copies.
    bf16x8 fAH[2][4], fAL[2][4], fBH[2][4], fBL[2][4];
    #pragma unroll
    for (int m = 0; m < 4; ++m) {
        fAH[0][m] = __builtin_bit_cast(bf16x8, pAh[m * 16]);
        fAL[0][m] = __builtin_bit_cast(bf16x8, pAl[m * 16]);
        fBH[0][m] = __builtin_bit_cast(bf16x8, pBh[m * 16]);
        fBL[0][m] = __builtin_bit_cast(bf16x8, pBl[m * 16]);
    }

    #pragma unroll
    for (int it = 0; it < DIM / 32; ++it) {
        const int cur = it & 1, nxt = cur ^ 1;
        if (it + 1 < DIM / 32) {                    // prefetch into the other buffer
            int o = (it + 1) * 512;
            #pragma unroll
            for (int m = 0; m < 4; ++m) {
                fAH[nxt][m] = __builtin_bit_cast(bf16x8, pAh[o + m * 16]);
                fAL[nxt][m] = __builtin_bit_cast(bf16x8, pAl[o + m * 16]);
                fBH[nxt][m] = __builtin_bit_cast(bf16x8, pBh[o + m * 16]);
                fBL[nxt][m] = __builtin_bit_cast(bf16x8, pBl[o + m * 16]);
            }
        }
        #pragma unroll
        for (int m = 0; m < 4; ++m)
            #pragma unroll
            for (int n = 0; n < 4; ++n) {
                acc[m][n] = __builtin_amdgcn_mfma_f32_16x16x32_bf16(fAH[cur][m], fBH[cur][n], acc[m][n], 0, 0, 0);
                acc[m][n] = __builtin_amdgcn_mfma_f32_16x16x32_bf16(fAH[cur][m], fBL[cur][n], acc[m][n], 0, 0, 0);
                acc[m][n] = __builtin_amdgcn_mfma_f32_16x16x32_bf16(fAL[cur][m], fBH[cur][n], acc[m][n], 0, 0, 0);
                // lo*lo pass dropped: ~2^-17 relative on Gram term
            }
    }

    // ---- epilogue: L2 -> sum of 5 Gaussian kernels -> reduce
    float scale = *scale_p;
    int ro_eff = ro + wr * 64, co_eff = co + wc * 64;
    float4 sqa4[4];
    float  sqbv[4];
    #pragma unroll
    for (int m = 0; m < 4; ++m) sqa4[m] = *(const float4*)&sq[ro_eff + m * 16 + lq * 4];
    #pragma unroll
    for (int n = 0; n < 4; ++n) sqbv[n] = sq[co_eff + n * 16 + lr];

    float tsum = 0.0f;
    #pragma unroll
    for (int m = 0; m < 4; ++m) {
        float sa[4] = {sqa4[m].x, sqa4[m].y, sqa4[m].z, sqa4[m].w};
        #pragma unroll
        for (int n = 0; n < 4; ++n) {
            #pragma unroll
            for (int r = 0; r < 4; ++r) {
                float L2  = sa[r] + sqbv[n] - 2.0f * acc[m][n][r];
                float u   = __builtin_amdgcn_exp2f(scale * L2);
                float u2  = u * u;
                float u4  = u2 * u2;
                float u8  = u4 * u4;
                float u16 = u8 * u8;
                tsum += u + u2 + u4 + u8 + u16;     // 5 kernel scales
            }
        }
    }

    #pragma unroll
    for (int off = 32; off; off >>= 1) tsum += __shfl_xor(tsum, off, 64);
    if (lane == 0) wsum[w] = tsum;
    __syncthreads();
    if (t == 0) {
        float tot = wsum[0] + wsum[1] + wsum[2] + wsum[3];
        float sgn = ((ro < HALF) == (co < HALF)) ? 1.0f : -1.0f;
        float wgt = (bi == bj) ? 1.0f : 2.0f;       // off-diag tiles stand for (i,j)+(j,i)
        atomicAdd(accum, (double)(sgn * wgt * tot));
    }

    // ---- last-finisher normalizes and writes the scalar output (fused k_fin)
    __threadfence();
    if (t == 0) isLast = (atomicAdd(cnt, 1) == NTILE - 1);
    __syncthreads();
    if (isLast && t == 0) {
        double v = atomicAdd(accum, 0.0);           // coherent read-back
        out[0] = (float)(v / ((double)HALF * (double)HALF));
    }
}

extern "C" void kernel_launch(void* const* d_in, const int* in_sizes, int n_in,
                              void* d_out, int out_size, void* d_ws, size_t ws_size,
                              hipStream_t stream) {
    const float* src = (const float*)d_in[0];
    const float* tgt = (const float*)d_in[1];
    float* out = (float*)d_out;

    char* ws = (char*)d_ws;
    int*    cnt1  = (int*)ws;                                    // 4 B
    int*    cnt2  = (int*)(ws + 4);                              // 4 B
    double* accum = (double*)(ws + 8);                           // 8 B
    float*  scale = (float*)(ws + 16);                           // 4 B
    float*  sq    = (float*)(ws + 64);                           // 32768 B
    float*  part  = (float*)(ws + 64 + 32768);                   // 256*256*4 B
    unsigned short* hi = (unsigned short*)(ws + 294976);         // 4 MB, 16B-aligned
    unsigned short* lo = (unsigned short*)(ws + 294976 + (size_t)NROWS * DIM * 2);

    hipMemsetAsync(ws, 0, 64, stream);              // counters + accum (+scale)
    k_conv <<<CONVB, 256, 0, stream>>>(src, tgt, hi, lo, sq, part, cnt1, scale);
    k_pairs<<<NTILE, 256, 0, stream>>>(hi, lo, sq, scale, accum, cnt2, out);
}

// Round 10
// 288.622 us; speedup vs baseline: 1.4259x; 1.1116x over previous
//
#include <hip/hip_runtime.h>

// MMD loss, N=4096 per side, D=256, fp32.
// R10: SINGLE-PASS bf16 MFMA Gram. Error analysis: bf16 rounding gives
//      dL2 ~ 0.05 RMS per pair vs bandwidth ~128; random part averages out
//      over 16.7M-entry means (~1e-7), systematic parts cancel across
//      XX/YY/XY (identical statistics) -> ~30x inside the 2.9e-5 threshold.
//      MFMA floor drops 22 -> 7.4 us; lo plane deleted (half the traffic).
//      k_pairs keeps R7's PROVEN code shape: arrays only indexed by
//      immediately-unrolled vars (R8/R9 lesson: loop-carried-index buffers
//      are never SROA-promoted -> scratch round-trips, 3x regression).
//      __launch_bounds__(256,3): demand ~130 regs < 170 cap -> 3 waves/SIMD.
//      Fused: k_scale into k_conv, k_fin into k_pairs (last-finisher).

#define NROWS 8192
#define HALF  4096
#define DIM   256
#define BM    128
#define CONVB 256         // k_conv blocks; 32 rows each (quarter panel)
#define NTILE 2080        // upper-tri tile count for 128-tiles (64 bands of 8)

typedef __bf16 bf16x8 __attribute__((ext_vector_type(8)));
typedef float f32x4 __attribute__((ext_vector_type(4)));
typedef unsigned short ushort8 __attribute__((ext_vector_type(8)));

__device__ __forceinline__ const float* row_ptr(const float* src, const float* tgt, int r) {
    return (r < HALF) ? (src + (size_t)r * DIM) : (tgt + (size_t)(r - HALF) * DIM);
}

__device__ __forceinline__ unsigned short bf16_rne(float x) {
    unsigned int u = __builtin_bit_cast(unsigned int, x);
    return (unsigned short)((u + 0x7FFFu + ((u >> 16) & 1u)) >> 16);
}

// --- Phase 0: fp32 -> hi bf16 plane (tiled) + sq[] + colsum partials; the
//     last-finishing block computes the bandwidth scale (fused k_scale). ---
// Tiled plane layout: 16B-granule index of (global row R, k-granule g) =
//   (R>>7)*4096 + g*128 + (R&127)        [panel-major, granule-major inside]
__global__ __launch_bounds__(256) void k_conv(const float* __restrict__ src,
                                              const float* __restrict__ tgt,
                                              unsigned short* __restrict__ hi,
                                              float* __restrict__ sq,
                                              float* __restrict__ part,
                                              int* __restrict__ cnt,
                                              float* __restrict__ scale) {
    __shared__ __align__(16) unsigned short sh_hi[32 * 32 * 8];  // 16 KB
    __shared__ float4 cs[4][64];
    __shared__ double sh[256];
    __shared__ int isLast;

    int w = threadIdx.x >> 6, lane = threadIdx.x & 63;
    int r0 = blockIdx.x * 32;                       // 32 rows per block
    int g  = lane >> 1, j = lane & 1;               // lane's float4 = half-granule
    float4 csum = {0.f, 0.f, 0.f, 0.f};
    #pragma unroll
    for (int i = 0; i < 8; ++i) {
        int rl  = w * 8 + i;                        // local row 0..31
        int row = r0 + rl;
        const float* rp = row_ptr(src, tgt, row);
        float4 v = ((const float4*)rp)[lane];       // coalesced: 64 lanes * 16 B
        float xs[4] = {v.x, v.y, v.z, v.w};
        unsigned short hs[4];
        #pragma unroll
        for (int k = 0; k < 4; ++k) hs[k] = bf16_rne(xs[k]);
        ushort4 h4 = {hs[0], hs[1], hs[2], hs[3]};
        int so = (g * 32 + rl) * 8 + j * 4;
        *(ushort4*)&sh_hi[so] = h4;
        csum.x += v.x; csum.y += v.y; csum.z += v.z; csum.w += v.w;
        float s = v.x * v.x + v.y * v.y + v.z * v.z + v.w * v.w;
        #pragma unroll
        for (int off = 32; off; off >>= 1) s += __shfl_xor(s, off, 64);
        if (lane == 0) sq[row] = s;
    }
    __syncthreads();
    // Coalesced tiled write-out: 1024 chunks of 16 B.
    int panel = blockIdx.x >> 2, quarter = blockIdx.x & 3;
    #pragma unroll
    for (int c = threadIdx.x; c < 1024; c += 256) {
        int gg = c >> 5, r = c & 31;
        size_t goff = (((size_t)panel * 32 + gg) * 128 + quarter * 32 + r) * 8;
        *(ushort8*)&hi[goff] = *(const ushort8*)&sh_hi[c * 8];
    }
    // colsum partials
    cs[w][lane] = csum;
    __syncthreads();
    if (w == 0) {
        float4 a = cs[0][lane], b = cs[1][lane], c = cs[2][lane], d = cs[3][lane];
        float4 tot = {a.x + b.x + c.x + d.x, a.y + b.y + c.y + d.y,
                      a.z + b.z + c.z + d.z, a.w + b.w + c.w + d.w};
        *(float4*)&part[(size_t)blockIdx.x * DIM + lane * 4] = tot;
    }

    // ---- last-finisher computes the bandwidth scale (fused k_scale)
    __threadfence();
    if (threadIdx.x == 0) isLast = (atomicAdd(cnt, 1) == CONVB - 1);
    __syncthreads();
    if (!isLast) return;
    __threadfence();                                // acquire: see all sq/part
    int t = threadIdx.x;
    double s1 = 0.0;
    for (int i = t; i < NROWS; i += 256) s1 += (double)sq[i];
    sh[t] = s1;
    __syncthreads();
    for (int off = 128; off; off >>= 1) {
        if (t < off) sh[t] += sh[t + off];
        __syncthreads();
    }
    double S1 = sh[0];
    __syncthreads();
    float c = 0.0f;
    for (int b = 0; b < CONVB; ++b) c += part[b * DIM + t];  // coalesced
    sh[t] = (double)c * (double)c;
    __syncthreads();
    for (int off = 128; off; off >>= 1) {
        if (t < off) sh[t] += sh[t + off];
        __syncthreads();
    }
    if (t == 0) {
        double S2    = sh[0];
        double n     = (double)NROWS;
        double sumL2 = 2.0 * n * S1 - 2.0 * S2;
        double bw    = sumL2 / (n * n - n) / 4.0;   // / KERNEL_MUL^(KERNEL_NUM//2)
        // u = exp(-L2/(16*bw)) = exp2(scale * L2)
        *scale = (float)(-1.0 / (16.0 * bw * 0.69314718055994530942));
    }
}

// --- Phase 2: barrier-free single-pass bf16 MFMA pair kernel ---
__global__ __launch_bounds__(256, 3) void k_pairs(const unsigned short* __restrict__ hi,
                                                  const float* __restrict__ sq,
                                                  const float* __restrict__ scale_p,
                                                  double* __restrict__ accum,
                                                  int* __restrict__ cnt,
                                                  float* __restrict__ out) {
    // Band decode: band k = bj/8; within band, bi-major, 8 consecutive columns.
    int id = blockIdx.x;
    int k = 0;
    while (k < 7 && 32 * (k + 1) * (k + 1) + 4 * (k + 1) <= id) ++k;
    int rem = id - (32 * k * k + 4 * k);
    int bi, col;
    if (rem < 64 * k) {
        bi = rem >> 3; col = rem & 7;
    } else {
        int r2 = rem - 64 * k;
        int jj = 0, c = 0;
        while (c + (8 - jj) <= r2) { c += (8 - jj); ++jj; }
        bi = 8 * k + jj; col = jj + (r2 - c);
    }
    int bj = 8 * k + col;

    __shared__ float wsum[4];
    __shared__ int isLast;

    int t    = threadIdx.x;
    int lane = t & 63;
    int w    = t >> 6;
    int wr   = w >> 1, wc = w & 1;                  // 2x2 wave grid, 64x64 each
    int lr   = lane & 15, lq = lane >> 4;
    int ro = bi * BM, co = bj * BM;

    size_t aBase = (size_t)bi * 4096 + lq * 128 + wr * 64 + lr;
    size_t bBase = (size_t)bj * 4096 + lq * 128 + wc * 64 + lr;
    const ushort8* pAh = (const ushort8*)hi + aBase;
    const ushort8* pBh = (const ushort8*)hi + bBase;

    f32x4 acc[4][4];
    #pragma unroll
    for (int m = 0; m < 4; ++m)
        #pragma unroll
        for (int n = 0; n < 4; ++n) acc[m][n] = (f32x4){0.f, 0.f, 0.f, 0.f};

    #pragma unroll
    for (int it = 0; it < DIM / 32; ++it) {
        // 8 coalesced loads (4 x 256B contiguous segments each), then 16 MFMAs.
        // Arrays indexed only by immediately-unrolled m/n -> pure registers.
        bf16x8 aH[4], bH[4];
        #pragma unroll
        for (int m = 0; m < 4; ++m)
            aH[m] = __builtin_bit_cast(bf16x8, pAh[it * 512 + m * 16]);
        #pragma unroll
        for (int n = 0; n < 4; ++n)
            bH[n] = __builtin_bit_cast(bf16x8, pBh[it * 512 + n * 16]);
        #pragma unroll
        for (int m = 0; m < 4; ++m)
            #pragma unroll
            for (int n = 0; n < 4; ++n)
                acc[m][n] = __builtin_amdgcn_mfma_f32_16x16x32_bf16(aH[m], bH[n], acc[m][n], 0, 0, 0);
    }

    // ---- epilogue: L2 -> sum of 5 Gaussian kernels -> reduce
    float scale = *scale_p;
    int ro_eff = ro + wr * 64, co_eff = co + wc * 64;
    float4 sqa4[4];
    float  sqbv[4];
    #pragma unroll
    for (int m = 0; m < 4; ++m) sqa4[m] = *(const float4*)&sq[ro_eff + m * 16 + lq * 4];
    #pragma unroll
    for (int n = 0; n < 4; ++n) sqbv[n] = sq[co_eff + n * 16 + lr];

    float tsum = 0.0f;
    #pragma unroll
    for (int m = 0; m < 4; ++m) {
        float sa[4] = {sqa4[m].x, sqa4[m].y, sqa4[m].z, sqa4[m].w};
        #pragma unroll
        for (int n = 0; n < 4; ++n) {
            #pragma unroll
            for (int r = 0; r < 4; ++r) {
                float L2  = sa[r] + sqbv[n] - 2.0f * acc[m][n][r];
                float u   = __builtin_amdgcn_exp2f(scale * L2);
                float u2  = u * u;
                float u4  = u2 * u2;
                float u8  = u4 * u4;
                float u16 = u8 * u8;
                tsum += u + u2 + u4 + u8 + u16;     // 5 kernel scales
            }
        }
    }

    #pragma unroll
    for (int off = 32; off; off >>= 1) tsum += __shfl_xor(tsum, off, 64);
    if (lane == 0) wsum[w] = tsum;
    __syncthreads();
    if (t == 0) {
        float tot = wsum[0] + wsum[1] + wsum[2] + wsum[3];
        float sgn = ((ro < HALF) == (co < HALF)) ? 1.0f : -1.0f;
        float wgt = (bi == bj) ? 1.0f : 2.0f;       // off-diag tiles stand for (i,j)+(j,i)
        atomicAdd(accum, (double)(sgn * wgt * tot));
    }

    // ---- last-finisher normalizes and writes the scalar output (fused k_fin)
    __threadfence();
    if (t == 0) isLast = (atomicAdd(cnt, 1) == NTILE - 1);
    __syncthreads();
    if (isLast && t == 0) {
        double v = atomicAdd(accum, 0.0);           // coherent read-back
        out[0] = (float)(v / ((double)HALF * (double)HALF));
    }
}

extern "C" void kernel_launch(void* const* d_in, const int* in_sizes, int n_in,
                              void* d_out, int out_size, void* d_ws, size_t ws_size,
                              hipStream_t stream) {
    const float* src = (const float*)d_in[0];
    const float* tgt = (const float*)d_in[1];
    float* out = (float*)d_out;

    char* ws = (char*)d_ws;
    int*    cnt1  = (int*)ws;                                    // 4 B
    int*    cnt2  = (int*)(ws + 4);                              // 4 B
    double* accum = (double*)(ws + 8);                           // 8 B
    float*  scale = (float*)(ws + 16);                           // 4 B
    float*  sq    = (float*)(ws + 64);                           // 32768 B
    float*  part  = (float*)(ws + 64 + 32768);                   // 256*256*4 B
    unsigned short* hi = (unsigned short*)(ws + 294976);         // 4 MB, 16B-aligned

    hipMemsetAsync(ws, 0, 64, stream);              // counters + accum (+scale)
    k_conv <<<CONVB, 256, 0, stream>>>(src, tgt, hi, sq, part, cnt1, scale);
    k_pairs<<<NTILE, 256, 0, stream>>>(hi, sq, scale, accum, cnt2, out);
}

// Round 11
// 124.968 us; speedup vs baseline: 3.2933x; 2.3096x over previous
//
#include <hip/hip_runtime.h>

// MMD loss, N=4096 per side, D=256, fp32.
// R11: single-pass bf16 MFMA Gram (numerics HW-verified in R10: absmax 0.0).
//      Structure = R7's proven 4-launch skeleton. CRITICAL: no __threadfence /
//      fused last-finisher anywhere — R8/R9/R10 triangulated that a per-block
//      device-scope fence forces L2 writeback/invalidate, flushing the hi
//      plane from every XCD's L2 (~2080 flushes) and turning all fragment
//      loads into ~600+cyc LLC misses (R10: MfmaUtil 3.6%, 186 us).
//      k_pairs: barrier-free K-loop, BK=64 batching (16 loads then 32 MFMAs
//      per unrolled iter -> 4 latency exposures instead of 8); frag arrays
//      indexed only by immediately-unrolled vars (SROA lesson from R8/R9).
//      Tiled hi plane (R6): each fragment load = 4x256B contiguous.

#define NROWS 8192
#define HALF  4096
#define DIM   256
#define BM    128
#define CONVB 256         // k_conv blocks; 32 rows each (quarter panel)
#define NTILE 2080        // upper-tri tile count for 128-tiles (64 bands of 8)

typedef __bf16 bf16x8 __attribute__((ext_vector_type(8)));
typedef float f32x4 __attribute__((ext_vector_type(4)));
typedef unsigned short ushort8 __attribute__((ext_vector_type(8)));

__device__ __forceinline__ const float* row_ptr(const float* src, const float* tgt, int r) {
    return (r < HALF) ? (src + (size_t)r * DIM) : (tgt + (size_t)(r - HALF) * DIM);
}

__device__ __forceinline__ unsigned short bf16_rne(float x) {
    unsigned int u = __builtin_bit_cast(unsigned int, x);
    return (unsigned short)((u + 0x7FFFu + ((u >> 16) & 1u)) >> 16);
}

// --- Phase 0: fp32 -> bf16 plane (tiled) + sq[] + colsum partials ---
// Tiled plane layout: 16B-granule index of (global row R, k-granule g) =
//   (R>>7)*4096 + g*128 + (R&127)        [panel-major, granule-major inside]
__global__ __launch_bounds__(256) void k_conv(const float* __restrict__ src,
                                              const float* __restrict__ tgt,
                                              unsigned short* __restrict__ hi,
                                              float* __restrict__ sq,
                                              float* __restrict__ part,
                                              double* __restrict__ accum) {
    __shared__ __align__(16) unsigned short sh_hi[32 * 32 * 8];  // 16 KB
    __shared__ float4 cs[4][64];

    int w = threadIdx.x >> 6, lane = threadIdx.x & 63;
    int r0 = blockIdx.x * 32;                       // 32 rows per block
    int g  = lane >> 1, j = lane & 1;               // lane's float4 = half-granule
    float4 csum = {0.f, 0.f, 0.f, 0.f};
    #pragma unroll
    for (int i = 0; i < 8; ++i) {
        int rl  = w * 8 + i;                        // local row 0..31
        int row = r0 + rl;
        const float* rp = row_ptr(src, tgt, row);
        float4 v = ((const float4*)rp)[lane];       // coalesced: 64 lanes * 16 B
        float xs[4] = {v.x, v.y, v.z, v.w};
        unsigned short hs[4];
        #pragma unroll
        for (int k = 0; k < 4; ++k) hs[k] = bf16_rne(xs[k]);
        ushort4 h4 = {hs[0], hs[1], hs[2], hs[3]};
        int so = (g * 32 + rl) * 8 + j * 4;
        *(ushort4*)&sh_hi[so] = h4;
        csum.x += v.x; csum.y += v.y; csum.z += v.z; csum.w += v.w;
        float s = v.x * v.x + v.y * v.y + v.z * v.z + v.w * v.w;
        #pragma unroll
        for (int off = 32; off; off >>= 1) s += __shfl_xor(s, off, 64);
        if (lane == 0) sq[row] = s;
    }
    __syncthreads();
    // Coalesced tiled write-out: 1024 chunks of 16 B.
    int panel = blockIdx.x >> 2, quarter = blockIdx.x & 3;
    #pragma unroll
    for (int c = threadIdx.x; c < 1024; c += 256) {
        int gg = c >> 5, r = c & 31;
        size_t goff = (((size_t)panel * 32 + gg) * 128 + quarter * 32 + r) * 8;
        *(ushort8*)&hi[goff] = *(const ushort8*)&sh_hi[c * 8];
    }
    // colsum partials
    cs[w][lane] = csum;
    __syncthreads();
    if (w == 0) {
        float4 a = cs[0][lane], b = cs[1][lane], c = cs[2][lane], d = cs[3][lane];
        float4 tot = {a.x + b.x + c.x + d.x, a.y + b.y + c.y + d.y,
                      a.z + b.z + c.z + d.z, a.w + b.w + c.w + d.w};
        *(float4*)&part[(size_t)blockIdx.x * DIM + lane * 4] = tot;
    }
    if (blockIdx.x == 0 && threadIdx.x == 0) *accum = 0.0;
}

// --- Phase 1: bandwidth -> exp2 scale factor ---
__global__ __launch_bounds__(256) void k_scale(const float* __restrict__ sq,
                                               const float* __restrict__ part,
                                               float* __restrict__ scale) {
    __shared__ double sh[256];
    int t = threadIdx.x;
    double s1 = 0.0;
    for (int i = t; i < NROWS; i += 256) s1 += (double)sq[i];
    sh[t] = s1;
    __syncthreads();
    for (int off = 128; off; off >>= 1) {
        if (t < off) sh[t] += sh[t + off];
        __syncthreads();
    }
    double S1 = sh[0];
    __syncthreads();
    float c = 0.0f;
    for (int b = 0; b < CONVB; ++b) c += part[b * DIM + t];  // coalesced
    sh[t] = (double)c * (double)c;
    __syncthreads();
    for (int off = 128; off; off >>= 1) {
        if (t < off) sh[t] += sh[t + off];
        __syncthreads();
    }
    if (t == 0) {
        double S2    = sh[0];
        double n     = (double)NROWS;
        double sumL2 = 2.0 * n * S1 - 2.0 * S2;
        double bw    = sumL2 / (n * n - n) / 4.0;   // / KERNEL_MUL^(KERNEL_NUM//2)
        // u = exp(-L2/(16*bw)) = exp2(scale * L2)
        *scale = (float)(-1.0 / (16.0 * bw * 0.69314718055994530942));
    }
}

// --- Phase 2: barrier-free single-pass bf16 MFMA pair kernel, BK=64 batch ---
__global__ __launch_bounds__(256, 2) void k_pairs(const unsigned short* __restrict__ hi,
                                                  const float* __restrict__ sq,
                                                  const float* __restrict__ scale_p,
                                                  double* __restrict__ accum) {
    // Band decode: band k = bj/8; within band, bi-major, 8 consecutive columns.
    int id = blockIdx.x;
    int k = 0;
    while (k < 7 && 32 * (k + 1) * (k + 1) + 4 * (k + 1) <= id) ++k;
    int rem = id - (32 * k * k + 4 * k);
    int bi, col;
    if (rem < 64 * k) {
        bi = rem >> 3; col = rem & 7;
    } else {
        int r2 = rem - 64 * k;
        int jj = 0, c = 0;
        while (c + (8 - jj) <= r2) { c += (8 - jj); ++jj; }
        bi = 8 * k + jj; col = jj + (r2 - c);
    }
    int bj = 8 * k + col;

    __shared__ float wsum[4];

    int t    = threadIdx.x;
    int lane = t & 63;
    int w    = t >> 6;
    int wr   = w >> 1, wc = w & 1;                  // 2x2 wave grid, 64x64 each
    int lr   = lane & 15, lq = lane >> 4;
    int ro = bi * BM, co = bj * BM;

    size_t aBase = (size_t)bi * 4096 + lq * 128 + wr * 64 + lr;
    size_t bBase = (size_t)bj * 4096 + lq * 128 + wc * 64 + lr;
    const ushort8* pAh = (const ushort8*)hi + aBase;
    const ushort8* pBh = (const ushort8*)hi + bBase;

    f32x4 acc[4][4];
    #pragma unroll
    for (int m = 0; m < 4; ++m)
        #pragma unroll
        for (int n = 0; n < 4; ++n) acc[m][n] = (f32x4){0.f, 0.f, 0.f, 0.f};

    #pragma unroll
    for (int it = 0; it < DIM / 64; ++it) {
        // 16 coalesced loads (two k32-chunks), then 32 MFMAs: 4 latency
        // exposures per block instead of 8. Arrays indexed only by
        // immediately-unrolled h/m/n -> pure registers (no scratch).
        bf16x8 aH[2][4], bH[2][4];
        #pragma unroll
        for (int h = 0; h < 2; ++h) {
            #pragma unroll
            for (int m = 0; m < 4; ++m) {
                aH[h][m] = __builtin_bit_cast(bf16x8, pAh[it * 1024 + h * 512 + m * 16]);
                bH[h][m] = __builtin_bit_cast(bf16x8, pBh[it * 1024 + h * 512 + m * 16]);
            }
        }
        #pragma unroll
        for (int h = 0; h < 2; ++h)
            #pragma unroll
            for (int m = 0; m < 4; ++m)
                #pragma unroll
                for (int n = 0; n < 4; ++n)
                    acc[m][n] = __builtin_amdgcn_mfma_f32_16x16x32_bf16(aH[h][m], bH[h][n], acc[m][n], 0, 0, 0);
    }

    // ---- epilogue: L2 -> sum of 5 Gaussian kernels -> reduce
    float scale = *scale_p;
    int ro_eff = ro + wr * 64, co_eff = co + wc * 64;
    float4 sqa4[4];
    float  sqbv[4];
    #pragma unroll
    for (int m = 0; m < 4; ++m) sqa4[m] = *(const float4*)&sq[ro_eff + m * 16 + lq * 4];
    #pragma unroll
    for (int n = 0; n < 4; ++n) sqbv[n] = sq[co_eff + n * 16 + lr];

    float tsum = 0.0f;
    #pragma unroll
    for (int m = 0; m < 4; ++m) {
        float sa[4] = {sqa4[m].x, sqa4[m].y, sqa4[m].z, sqa4[m].w};
        #pragma unroll
        for (int n = 0; n < 4; ++n) {
            #pragma unroll
            for (int r = 0; r < 4; ++r) {
                float L2  = sa[r] + sqbv[n] - 2.0f * acc[m][n][r];
                float u   = __builtin_amdgcn_exp2f(scale * L2);
                float u2  = u * u;
                float u4  = u2 * u2;
                float u8  = u4 * u4;
                float u16 = u8 * u8;
                tsum += u + u2 + u4 + u8 + u16;     // 5 kernel scales
            }
        }
    }

    #pragma unroll
    for (int off = 32; off; off >>= 1) tsum += __shfl_xor(tsum, off, 64);
    if (lane == 0) wsum[w] = tsum;
    __syncthreads();
    if (t == 0) {
        float tot = wsum[0] + wsum[1] + wsum[2] + wsum[3];
        float sgn = ((ro < HALF) == (co < HALF)) ? 1.0f : -1.0f;
        float wgt = (bi == bj) ? 1.0f : 2.0f;       // off-diag tiles stand for (i,j)+(j,i)
        atomicAdd(accum, (double)(sgn * wgt * tot));
    }
}

// --- Finalize: mean normalization ---
__global__ void k_fin(const double* __restrict__ accum, float* __restrict__ out) {
    out[0] = (float)(*accum / ((double)HALF * (double)HALF));
}

extern "C" void kernel_launch(void* const* d_in, const int* in_sizes, int n_in,
                              void* d_out, int out_size, void* d_ws, size_t ws_size,
                              hipStream_t stream) {
    const float* src = (const float*)d_in[0];
    const float* tgt = (const float*)d_in[1];
    float* out = (float*)d_out;

    char* ws = (char*)d_ws;
    double* accum = (double*)ws;                                 // 8 B
    float*  scale = (float*)(ws + 16);                           // 4 B
    float*  sq    = (float*)(ws + 64);                           // 32768 B
    float*  part  = (float*)(ws + 64 + 32768);                   // 256*256*4 B
    unsigned short* hi = (unsigned short*)(ws + 294976);         // 4 MB, 16B-aligned

    k_conv <<<CONVB, 256, 0, stream>>>(src, tgt, hi, sq, part, accum);
    k_scale<<<1, 256, 0, stream>>>(sq, part, scale);
    k_pairs<<<NTILE, 256, 0, stream>>>(hi, sq, scale, accum);
    k_fin  <<<1, 1, 0, stream>>>(accum, out);
}

// Round 12
// 116.330 us; speedup vs baseline: 3.5379x; 1.0742x over previous
//
#include <hip/hip_runtime.h>

// MMD loss, N=4096 per side, D=256, fp32.
// R12: single-pass bf16 MFMA Gram (HW-verified R10/R11: absmax 0.0).
//      Changes vs R11 (125 us, k_pairs 48.5):
//      1) k_pairs __launch_bounds__(256,4): VGPR 60 + 64 acc-AGPR = 124 <= 128
//         regs/wave -> 4 waves/SIMD (was 2) for 2x latency hiding.
//      2) k_scale de-serialized: per-block S1 partials from k_conv (256 doubles
//         instead of 8192 floats) + 4 independent accumulators + unroll 16 on
//         the part-column loop (was a ~600-cyc-per-batch serial chain, ~25 us).
//      NO __threadfence anywhere (R8-R10 lesson: per-block device fence
//      flushes L2 -> all fragment loads become LLC misses, 3x regression).
//      k_pairs: barrier-free K-loop, BK=64 batch, frag arrays indexed only by
//      immediately-unrolled vars (R8/R9 SROA lesson). Tiled bf16 plane (R6).

#define NROWS 8192
#define HALF  4096
#define DIM   256
#define BM    128
#define CONVB 256         // k_conv blocks; 32 rows each (quarter panel)
#define NTILE 2080        // upper-tri tile count for 128-tiles (64 bands of 8)

typedef __bf16 bf16x8 __attribute__((ext_vector_type(8)));
typedef float f32x4 __attribute__((ext_vector_type(4)));
typedef unsigned short ushort8 __attribute__((ext_vector_type(8)));

__device__ __forceinline__ const float* row_ptr(const float* src, const float* tgt, int r) {
    return (r < HALF) ? (src + (size_t)r * DIM) : (tgt + (size_t)(r - HALF) * DIM);
}

__device__ __forceinline__ unsigned short bf16_rne(float x) {
    unsigned int u = __builtin_bit_cast(unsigned int, x);
    return (unsigned short)((u + 0x7FFFu + ((u >> 16) & 1u)) >> 16);
}

// --- Phase 0: fp32 -> bf16 plane (tiled) + sq[] + colsum/S1 partials ---
// Tiled plane layout: 16B-granule index of (global row R, k-granule g) =
//   (R>>7)*4096 + g*128 + (R&127)        [panel-major, granule-major inside]
__global__ __launch_bounds__(256) void k_conv(const float* __restrict__ src,
                                              const float* __restrict__ tgt,
                                              unsigned short* __restrict__ hi,
                                              float* __restrict__ sq,
                                              float* __restrict__ part,
                                              double* __restrict__ parts1,
                                              double* __restrict__ accum) {
    __shared__ __align__(16) unsigned short sh_hi[32 * 32 * 8];  // 16 KB
    __shared__ float4 cs[4][64];
    __shared__ double s1s[4];

    int w = threadIdx.x >> 6, lane = threadIdx.x & 63;
    int r0 = blockIdx.x * 32;                       // 32 rows per block
    int g  = lane >> 1, j = lane & 1;               // lane's float4 = half-granule
    float4 csum = {0.f, 0.f, 0.f, 0.f};
    double s1w = 0.0;                               // this wave's sum of row-sq
    #pragma unroll
    for (int i = 0; i < 8; ++i) {
        int rl  = w * 8 + i;                        // local row 0..31
        int row = r0 + rl;
        const float* rp = row_ptr(src, tgt, row);
        float4 v = ((const float4*)rp)[lane];       // coalesced: 64 lanes * 16 B
        float xs[4] = {v.x, v.y, v.z, v.w};
        unsigned short hs[4];
        #pragma unroll
        for (int k = 0; k < 4; ++k) hs[k] = bf16_rne(xs[k]);
        ushort4 h4 = {hs[0], hs[1], hs[2], hs[3]};
        int so = (g * 32 + rl) * 8 + j * 4;
        *(ushort4*)&sh_hi[so] = h4;
        csum.x += v.x; csum.y += v.y; csum.z += v.z; csum.w += v.w;
        float s = v.x * v.x + v.y * v.y + v.z * v.z + v.w * v.w;
        #pragma unroll
        for (int off = 32; off; off >>= 1) s += __shfl_xor(s, off, 64);
        if (lane == 0) { sq[row] = s; s1w += (double)s; }
    }
    __syncthreads();
    // Coalesced tiled write-out: 1024 chunks of 16 B.
    int panel = blockIdx.x >> 2, quarter = blockIdx.x & 3;
    #pragma unroll
    for (int c = threadIdx.x; c < 1024; c += 256) {
        int gg = c >> 5, r = c & 31;
        size_t goff = (((size_t)panel * 32 + gg) * 128 + quarter * 32 + r) * 8;
        *(ushort8*)&hi[goff] = *(const ushort8*)&sh_hi[c * 8];
    }
    // colsum + S1 partials
    cs[w][lane] = csum;
    if (lane == 0) s1s[w] = s1w;
    __syncthreads();
    if (w == 0) {
        float4 a = cs[0][lane], b = cs[1][lane], c = cs[2][lane], d = cs[3][lane];
        float4 tot = {a.x + b.x + c.x + d.x, a.y + b.y + c.y + d.y,
                      a.z + b.z + c.z + d.z, a.w + b.w + c.w + d.w};
        *(float4*)&part[(size_t)blockIdx.x * DIM + lane * 4] = tot;
        if (lane == 0) parts1[blockIdx.x] = s1s[0] + s1s[1] + s1s[2] + s1s[3];
    }
    if (blockIdx.x == 0 && threadIdx.x == 0) *accum = 0.0;
}

// --- Phase 1: bandwidth -> exp2 scale factor (pipelined reductions) ---
__global__ __launch_bounds__(256) void k_scale(const double* __restrict__ parts1,
                                               const float* __restrict__ part,
                                               float* __restrict__ scale) {
    __shared__ double sh[256];
    int t = threadIdx.x;
    // S1: 256 block partials, one per thread.
    sh[t] = parts1[t];
    __syncthreads();
    for (int off = 128; off; off >>= 1) {
        if (t < off) sh[t] += sh[t + off];
        __syncthreads();
    }
    double S1 = sh[0];
    __syncthreads();
    // S2: column sums over CONVB blocks, 4 independent accumulators + unroll
    // -> ~16 outstanding loads (was a serial ~600-cyc-per-batch chain).
    float c0 = 0.f, c1 = 0.f, c2 = 0.f, c3 = 0.f;
    #pragma unroll 16
    for (int b = 0; b < CONVB; b += 4) {
        c0 += part[(b + 0) * DIM + t];
        c1 += part[(b + 1) * DIM + t];
        c2 += part[(b + 2) * DIM + t];
        c3 += part[(b + 3) * DIM + t];
    }
    double c = (double)((c0 + c1) + (c2 + c3));
    sh[t] = c * c;
    __syncthreads();
    for (int off = 128; off; off >>= 1) {
        if (t < off) sh[t] += sh[t + off];
        __syncthreads();
    }
    if (t == 0) {
        double S2    = sh[0];
        double n     = (double)NROWS;
        double sumL2 = 2.0 * n * S1 - 2.0 * S2;
        double bw    = sumL2 / (n * n - n) / 4.0;   // / KERNEL_MUL^(KERNEL_NUM//2)
        // u = exp(-L2/(16*bw)) = exp2(scale * L2)
        *scale = (float)(-1.0 / (16.0 * bw * 0.69314718055994530942));
    }
}

// --- Phase 2: barrier-free single-pass bf16 MFMA pair kernel, BK=64 batch ---
__global__ __launch_bounds__(256, 4) void k_pairs(const unsigned short* __restrict__ hi,
                                                  const float* __restrict__ sq,
                                                  const float* __restrict__ scale_p,
                                                  double* __restrict__ accum) {
    // Band decode: band k = bj/8; within band, bi-major, 8 consecutive columns.
    int id = blockIdx.x;
    int k = 0;
    while (k < 7 && 32 * (k + 1) * (k + 1) + 4 * (k + 1) <= id) ++k;
    int rem = id - (32 * k * k + 4 * k);
    int bi, col;
    if (rem < 64 * k) {
        bi = rem >> 3; col = rem & 7;
    } else {
        int r2 = rem - 64 * k;
        int jj = 0, c = 0;
        while (c + (8 - jj) <= r2) { c += (8 - jj); ++jj; }
        bi = 8 * k + jj; col = jj + (r2 - c);
    }
    int bj = 8 * k + col;

    __shared__ float wsum[4];

    int t    = threadIdx.x;
    int lane = t & 63;
    int w    = t >> 6;
    int wr   = w >> 1, wc = w & 1;                  // 2x2 wave grid, 64x64 each
    int lr   = lane & 15, lq = lane >> 4;
    int ro = bi * BM, co = bj * BM;

    size_t aBase = (size_t)bi * 4096 + lq * 128 + wr * 64 + lr;
    size_t bBase = (size_t)bj * 4096 + lq * 128 + wc * 64 + lr;
    const ushort8* pAh = (const ushort8*)hi + aBase;
    const ushort8* pBh = (const ushort8*)hi + bBase;

    f32x4 acc[4][4];
    #pragma unroll
    for (int m = 0; m < 4; ++m)
        #pragma unroll
        for (int n = 0; n < 4; ++n) acc[m][n] = (f32x4){0.f, 0.f, 0.f, 0.f};

    #pragma unroll
    for (int it = 0; it < DIM / 64; ++it) {
        // 16 coalesced loads (two k32-chunks), then 32 MFMAs: 4 latency
        // exposures per block. Arrays indexed only by immediately-unrolled
        // h/m/n -> pure registers (no scratch).
        bf16x8 aH[2][4], bH[2][4];
        #pragma unroll
        for (int h = 0; h < 2; ++h) {
            #pragma unroll
            for (int m = 0; m < 4; ++m) {
                aH[h][m] = __builtin_bit_cast(bf16x8, pAh[it * 1024 + h * 512 + m * 16]);
                bH[h][m] = __builtin_bit_cast(bf16x8, pBh[it * 1024 + h * 512 + m * 16]);
            }
        }
        #pragma unroll
        for (int h = 0; h < 2; ++h)
            #pragma unroll
            for (int m = 0; m < 4; ++m)
                #pragma unroll
                for (int n = 0; n < 4; ++n)
                    acc[m][n] = __builtin_amdgcn_mfma_f32_16x16x32_bf16(aH[h][m], bH[h][n], acc[m][n], 0, 0, 0);
    }

    // ---- epilogue: L2 -> sum of 5 Gaussian kernels -> reduce
    float scale = *scale_p;
    int ro_eff = ro + wr * 64, co_eff = co + wc * 64;
    float4 sqa4[4];
    float  sqbv[4];
    #pragma unroll
    for (int m = 0; m < 4; ++m) sqa4[m] = *(const float4*)&sq[ro_eff + m * 16 + lq * 4];
    #pragma unroll
    for (int n = 0; n < 4; ++n) sqbv[n] = sq[co_eff + n * 16 + lr];

    float tsum = 0.0f;
    #pragma unroll
    for (int m = 0; m < 4; ++m) {
        float sa[4] = {sqa4[m].x, sqa4[m].y, sqa4[m].z, sqa4[m].w};
        #pragma unroll
        for (int n = 0; n < 4; ++n) {
            #pragma unroll
            for (int r = 0; r < 4; ++r) {
                float L2  = sa[r] + sqbv[n] - 2.0f * acc[m][n][r];
                float u   = __builtin_amdgcn_exp2f(scale * L2);
                float u2  = u * u;
                float u4  = u2 * u2;
                float u8  = u4 * u4;
                float u16 = u8 * u8;
                tsum += u + u2 + u4 + u8 + u16;     // 5 kernel scales
            }
        }
    }

    #pragma unroll
    for (int off = 32; off; off >>= 1) tsum += __shfl_xor(tsum, off, 64);
    if (lane == 0) wsum[w] = tsum;
    __syncthreads();
    if (t == 0) {
        float tot = wsum[0] + wsum[1] + wsum[2] + wsum[3];
        float sgn = ((ro < HALF) == (co < HALF)) ? 1.0f : -1.0f;
        float wgt = (bi == bj) ? 1.0f : 2.0f;       // off-diag tiles stand for (i,j)+(j,i)
        atomicAdd(accum, (double)(sgn * wgt * tot));
    }
}

// --- Finalize: mean normalization ---
__global__ void k_fin(const double* __restrict__ accum, float* __restrict__ out) {
    out[0] = (float)(*accum / ((double)HALF * (double)HALF));
}

extern "C" void kernel_launch(void* const* d_in, const int* in_sizes, int n_in,
                              void* d_out, int out_size, void* d_ws, size_t ws_size,
                              hipStream_t stream) {
    const float* src = (const float*)d_in[0];
    const float* tgt = (const float*)d_in[1];
    float* out = (float*)d_out;

    char* ws = (char*)d_ws;
    double* accum  = (double*)ws;                                // 8 B
    float*  scale  = (float*)(ws + 16);                          // 4 B
    float*  sq     = (float*)(ws + 64);                          // 32768 B
    float*  part   = (float*)(ws + 64 + 32768);                  // 256*256*4 B
    double* parts1 = (double*)(ws + 64 + 32768 + 262144);        // 256*8 B
    unsigned short* hi = (unsigned short*)(ws + 297024);         // 4 MB, 16B-aligned

    k_conv <<<CONVB, 256, 0, stream>>>(src, tgt, hi, sq, part, parts1, accum);
    k_scale<<<1, 256, 0, stream>>>(parts1, part, scale);
    k_pairs<<<NTILE, 256, 0, stream>>>(hi, sq, scale, accum);
    k_fin  <<<1, 1, 0, stream>>>(accum, out);
}